// Round 1
// baseline (900.472 us; speedup 1.0000x reference)
//
#include <hip/hip_runtime.h>

#define N_NODES 50000
#define BATCH   4
#define N_EDGES 500000
#define H_SIZE  64

#define NSEG   (BATCH * N_NODES)            // 200,000 segments (b, src)
#define NEDGE  (BATCH * N_EDGES)            // 2,000,000 edges
#define NHEL   ((long long)BATCH * N_NODES * H_SIZE)   // 12.8M H elems

#define SPB    128                          // segments per bucket (seg>>7)
#define CB     ((NSEG + SPB - 1) / SPB)     // 1563 buckets
#define CHUNK  8192                         // edges per hist/scatter block
#define NCHUNK ((NEDGE + CHUNK - 1) / CHUNK) // 245 chunks
#define NELEM  (CB * NCHUNK)                // 382,935
#define NTOT   (NELEM + 1)                  // +1 sentinel (total)

#define SCAN_B 1024
#define NB1    ((NTOT + SCAN_B - 1) / SCAN_B)   // 374 (<512)

// ---------- Phase 1: per-(bucket, chunk) histogram + fused H->bf16 cvt ----
__global__ __launch_bounds__(1024) void hist_kernel(
    const float* __restrict__ ew, int* __restrict__ hmat,
    const float* __restrict__ H, ushort* __restrict__ Hb16, int do_cvt)
{
    __shared__ int h[CB];
    const int c = blockIdx.x;
    for (int i = threadIdx.x; i < CB; i += 1024) h[i] = 0;
    __syncthreads();
    int e0 = c * CHUNK;
    int e1 = e0 + CHUNK; if (e1 > NEDGE) e1 = NEDGE;
    for (int e = e0 + threadIdx.x; e < e1; e += 1024) {
        int b = e / N_EDGES;
        int src = (int)ew[(long long)e * 3];
        src = min(max(src, 0), N_NODES - 1);
        atomicAdd(&h[(b * N_NODES + src) >> 7], 1);
    }
    __syncthreads();
    for (int cb = threadIdx.x; cb < CB; cb += 1024)
        hmat[(long long)cb * NCHUNK + c] = h[cb];

    // fused cvt: H fp32 -> bf16 (RNE), grid-stride over all 245x1024 threads
    if (do_cvt) {
        const long long stride = (long long)NCHUNK * 1024 * 4;
        for (long long i = ((long long)c * 1024 + threadIdx.x) * 4; i < NHEL;
             i += stride) {
            float4 f = *(const float4*)(H + i);
            ushort4 u;
            uint v;
            v = __float_as_uint(f.x); u.x = (ushort)((v + 0x7FFF + ((v >> 16) & 1)) >> 16);
            v = __float_as_uint(f.y); u.y = (ushort)((v + 0x7FFF + ((v >> 16) & 1)) >> 16);
            v = __float_as_uint(f.z); u.z = (ushort)((v + 0x7FFF + ((v >> 16) & 1)) >> 16);
            v = __float_as_uint(f.w); u.w = (ushort)((v + 0x7FFF + ((v >> 16) & 1)) >> 16);
            *(ushort4*)(Hb16 + i) = u;
        }
    }
}

// ---------- Phase 2: exclusive scan over NTOT (scan3 fused into consumers) -
__global__ __launch_bounds__(SCAN_B) void scan1_kernel(
    int* __restrict__ data, int* __restrict__ bsum)
{
    __shared__ int sm[SCAN_B];
    int i = blockIdx.x * SCAN_B + threadIdx.x;
    int v = (i < NELEM) ? data[i] : 0;
    sm[threadIdx.x] = v;
    __syncthreads();
    for (int off = 1; off < SCAN_B; off <<= 1) {
        int t = (threadIdx.x >= off) ? sm[threadIdx.x - off] : 0;
        __syncthreads();
        sm[threadIdx.x] += t;
        __syncthreads();
    }
    if (i < NTOT) data[i] = sm[threadIdx.x] - v;
    if (threadIdx.x == SCAN_B - 1) bsum[blockIdx.x] = sm[SCAN_B - 1];
}

__global__ __launch_bounds__(512) void scan2_kernel(int* __restrict__ bsum)
{
    __shared__ int sm[512];
    int v = (threadIdx.x < NB1) ? bsum[threadIdx.x] : 0;
    sm[threadIdx.x] = v;
    __syncthreads();
    for (int off = 1; off < 512; off <<= 1) {
        int t = (threadIdx.x >= off) ? sm[threadIdx.x - off] : 0;
        __syncthreads();
        sm[threadIdx.x] += t;
        __syncthreads();
    }
    if (threadIdx.x < NB1) bsum[threadIdx.x] = sm[threadIdx.x] - v;
}

// ---------- Phase 3: partitioned scatter into coarse buckets ----------
// pair.x = (b<<24) | (seg&127)<<16 | dst ; pair.y = bits(w).
// scan3 fused: global offset = offs[x] + bsum[x>>10].
__global__ __launch_bounds__(1024) void scatter_kernel(
    const float* __restrict__ ew, const int* __restrict__ offs,
    const int* __restrict__ bsum, int2* __restrict__ pair)
{
    __shared__ int lcur[CB];
    const int c = blockIdx.x;
    for (int i = threadIdx.x; i < CB; i += 1024) lcur[i] = 0;
    __syncthreads();
    int e0 = c * CHUNK;
    int e1 = e0 + CHUNK; if (e1 > NEDGE) e1 = NEDGE;
    for (int e = e0 + threadIdx.x; e < e1; e += 1024) {
        long long eb = (long long)e * 3;
        int b = e / N_EDGES;
        int src = (int)ew[eb];
        int dst = (int)ew[eb + 1];
        float w = ew[eb + 2];
        src = min(max(src, 0), N_NODES - 1);
        dst = min(max(dst, 0), N_NODES - 1);
        int seg = b * N_NODES + src;
        int cb = seg >> 7, sl = seg & (SPB - 1);
        long long oi = (long long)cb * NCHUNK + c;
        int pos = offs[oi] + bsum[(int)(oi >> 10)] + atomicAdd(&lcur[cb], 1);
        pos = min(max(pos, 0), NEDGE - 1);
        int2 v; v.x = (b << 24) | (sl << 16) | dst; v.y = __float_as_int(w);
        pair[pos] = v;
    }
}

// ---------- Phase 4: bucket gather-accumulate (replaces sort + gather) -----
// One block per bucket; acc[128][64] fp32 in LDS (32 KB -> 4 blocks/CU,
// 32 waves/CU). Half-wave (32 lanes) per edge, uint load = 2 bf16 feats.
// Swizzled acc layout: feature f -> col (f>>1) + (f&1)*32, so each
// ds_add_f32 hits 32 distinct banks per half-wave (2-way alias = free).
__global__ __launch_bounds__(512) void bgather_bf16(
    const ushort* __restrict__ Hb16, const int* __restrict__ hmat,
    const int* __restrict__ bsum, const int2* __restrict__ pair,
    float* __restrict__ out)
{
    __shared__ __align__(16) float acc[SPB * 64];   // 32 KB
    const int cb = blockIdx.x;
    for (int i = threadIdx.x * 4; i < SPB * 64; i += 512 * 4)
        *(float4*)(acc + i) = make_float4(0.f, 0.f, 0.f, 0.f);

    long long i0 = (long long)cb * NCHUNK;
    long long i1 = i0 + NCHUNK;                 // cb=CB-1 -> sentinel
    int base = hmat[i0] + bsum[(int)(i0 >> 10)];
    int endv = hmat[i1] + bsum[(int)(i1 >> 10)];
    base = min(max(base, 0), NEDGE);
    endv = min(max(endv, base), NEDGE);
    __syncthreads();

    const int es  = threadIdx.x >> 5;           // edge slot 0..15
    const int sub = threadIdx.x & 31;           // feature-pair lane
    const uint* H32 = (const uint*)Hb16;

    for (int i = base; i < endv; i += 64) {     // 16 slots x 4 unroll
        int2 p[4];
        #pragma unroll
        for (int j = 0; j < 4; ++j) {
            int e = i + 16 * j + es;
            p[j] = pair[(e < endv) ? e : base];
        }
        uint hv[4];
        #pragma unroll
        for (int j = 0; j < 4; ++j) {
            int dst = p[j].x & 0xFFFF;
            int bb  = (p[j].x >> 24) & 3;
            hv[j] = H32[((bb * N_NODES + dst) << 5) + sub];
        }
        #pragma unroll
        for (int j = 0; j < 4; ++j) {
            int e = i + 16 * j + es;
            float w = (e < endv) ? __int_as_float(p[j].y) : 0.0f;
            int sl = (p[j].x >> 16) & 0xFF;
            float f0 = __uint_as_float(hv[j] << 16);          // feat 2*sub
            float f1 = __uint_as_float(hv[j] & 0xFFFF0000u);  // feat 2*sub+1
            atomicAdd(&acc[sl * 64 + sub],      w * f0);
            atomicAdd(&acc[sl * 64 + 32 + sub], w * f1);
        }
    }
    __syncthreads();

    // writeout: feature f of row sl lives at acc[sl*64 + (f>>1) + (f&1)*32]
    for (int idx = threadIdx.x; idx < SPB * 16; idx += 512) {
        int sl = idx >> 4, fq = idx & 15;
        long long seg = ((long long)cb << 7) + sl;
        if (seg >= NSEG) break;
        const float* a = acc + sl * 64;
        float4 v;
        v.x = a[2 * fq];
        v.y = a[2 * fq + 32];
        v.z = a[2 * fq + 1];
        v.w = a[2 * fq + 33];
        ((float4*)out)[seg * 16 + fq] = v;
    }
}

// fp32 variant (workspace too small for the bf16 mirror)
__global__ __launch_bounds__(512) void bgather_f32(
    const float* __restrict__ H, const int* __restrict__ hmat,
    const int* __restrict__ bsum, const int2* __restrict__ pair,
    float* __restrict__ out)
{
    __shared__ __align__(16) float acc[SPB * 64];
    const int cb = blockIdx.x;
    for (int i = threadIdx.x * 4; i < SPB * 64; i += 512 * 4)
        *(float4*)(acc + i) = make_float4(0.f, 0.f, 0.f, 0.f);

    long long i0 = (long long)cb * NCHUNK;
    long long i1 = i0 + NCHUNK;
    int base = hmat[i0] + bsum[(int)(i0 >> 10)];
    int endv = hmat[i1] + bsum[(int)(i1 >> 10)];
    base = min(max(base, 0), NEDGE);
    endv = min(max(endv, base), NEDGE);
    __syncthreads();

    const int es  = threadIdx.x >> 5;
    const int sub = threadIdx.x & 31;
    const float2* H2 = (const float2*)H;

    for (int i = base; i < endv; i += 64) {
        int2 p[4];
        #pragma unroll
        for (int j = 0; j < 4; ++j) {
            int e = i + 16 * j + es;
            p[j] = pair[(e < endv) ? e : base];
        }
        float2 hv[4];
        #pragma unroll
        for (int j = 0; j < 4; ++j) {
            int dst = p[j].x & 0xFFFF;
            int bb  = (p[j].x >> 24) & 3;
            hv[j] = H2[((bb * N_NODES + dst) << 5) + sub];
        }
        #pragma unroll
        for (int j = 0; j < 4; ++j) {
            int e = i + 16 * j + es;
            float w = (e < endv) ? __int_as_float(p[j].y) : 0.0f;
            int sl = (p[j].x >> 16) & 0xFF;
            atomicAdd(&acc[sl * 64 + sub],      w * hv[j].x);
            atomicAdd(&acc[sl * 64 + 32 + sub], w * hv[j].y);
        }
    }
    __syncthreads();

    for (int idx = threadIdx.x; idx < SPB * 16; idx += 512) {
        int sl = idx >> 4, fq = idx & 15;
        long long seg = ((long long)cb << 7) + sl;
        if (seg >= NSEG) break;
        const float* a = acc + sl * 64;
        float4 v;
        v.x = a[2 * fq];
        v.y = a[2 * fq + 32];
        v.z = a[2 * fq + 1];
        v.w = a[2 * fq + 33];
        ((float4*)out)[seg * 16 + fq] = v;
    }
}

// ---------- Fallback path (ws too small): zero + atomic scatter ----------
__global__ __launch_bounds__(256) void zero_kernel(int* __restrict__ p, long long n)
{
    long long i = (long long)blockIdx.x * blockDim.x + threadIdx.x;
    if (i < n) p[i] = 0;
}

__global__ __launch_bounds__(256) void atomic_kernel(
    const float* __restrict__ H, const float* __restrict__ ew,
    float* __restrict__ out)
{
    const long long gid = (long long)blockIdx.x * blockDim.x + threadIdx.x;
    const long long wave = gid >> 6;
    const int lane = threadIdx.x & 63;
    if (wave >= (long long)NEDGE) return;
    const int b = (int)(wave / N_EDGES);
    const long long ebase = wave * 3;
    const int src = (int)ew[ebase + 0];
    const int dst = (int)ew[ebase + 1];
    const float w = ew[ebase + 2];
    atomicAdd(&out[((long long)b * N_NODES + src) * H_SIZE + lane],
              w * H[((long long)b * N_NODES + dst) * H_SIZE + lane]);
}

extern "C" void kernel_launch(void* const* d_in, const int* in_sizes, int n_in,
                              void* d_out, int out_size, void* d_ws, size_t ws_size,
                              hipStream_t stream) {
    const float* H  = (const float*)d_in[0];   // (B, N, 64) fp32
    const float* ew = (const float*)d_in[1];   // (B, E, 3) fp32
    float* out = (float*)d_out;                // (B, N, 64) fp32

    // ws layout: hmat[NTOT] | bsum[512] | (8B-align) pair[NEDGE]int2 |
    //            (128B-align) Hb16[12.8M ushort]
    const size_t ioff = (((size_t)NTOT + 512) * 4 + 7) & ~(size_t)7;
    const size_t need_base = ioff + (size_t)NEDGE * 8;
    const size_t hoff = (need_base + 127) & ~(size_t)127;
    const size_t need_full = hoff + (size_t)NHEL * 2;   // ~43.1 MB

    if (ws_size < need_base) {
        long long n = out_size;
        zero_kernel<<<(unsigned)((n + 255) / 256), 256, 0, stream>>>((int*)out, n);
        const long long total = (long long)NEDGE * 64;
        atomic_kernel<<<(unsigned)((total + 255) / 256), 256, 0, stream>>>(H, ew, out);
        return;
    }

    int* hmat = (int*)d_ws;
    int* bsum = hmat + NTOT;
    int2* pair = (int2*)((char*)d_ws + ioff);
    ushort* Hb16 = (ushort*)((char*)d_ws + hoff);

    const bool full = (ws_size >= need_full);

    hist_kernel<<<NCHUNK, 1024, 0, stream>>>(ew, hmat, H, Hb16, full ? 1 : 0);
    scan1_kernel<<<NB1, SCAN_B, 0, stream>>>(hmat, bsum);
    scan2_kernel<<<1, 512, 0, stream>>>(bsum);
    scatter_kernel<<<NCHUNK, 1024, 0, stream>>>(ew, hmat, bsum, pair);

    if (full) {
        bgather_bf16<<<CB, 512, 0, stream>>>(Hb16, hmat, bsum, pair, out);
    } else {
        bgather_f32<<<CB, 512, 0, stream>>>(H, hmat, bsum, pair, out);
    }
}

// Round 2
// 204.866 us; speedup vs baseline: 4.3954x; 4.3954x over previous
//
#include <hip/hip_runtime.h>

#define N_NODES 50000
#define BATCH   4
#define N_EDGES 500000
#define H_SIZE  64

#define NSEG   (BATCH * N_NODES)            // 200,000 segments (b, src)
#define NEDGE  (BATCH * N_EDGES)            // 2,000,000 edges
#define NHEL   ((long long)BATCH * N_NODES * H_SIZE)   // 12.8M H elems

#define SPB    128                          // segments per bucket (seg>>7)
#define CB     ((NSEG + SPB - 1) / SPB)     // 1563 buckets
#define CHUNK  8192                         // edges per hist/scatter block
#define NCHUNK ((NEDGE + CHUNK - 1) / CHUNK) // 245 chunks
#define NELEM  (CB * NCHUNK)                // 382,935
#define NTOT   (NELEM + 1)                  // +1 sentinel (total)

#define SCAN_B 1024
#define NB1    ((NTOT + SCAN_B - 1) / SCAN_B)   // 374 (<512)

#define CAP    2048   // per-bucket LDS edge cap (mean 1280, ~21 sigma margin)

// ---------- Phase 1: per-(bucket, chunk) histogram + fused H->bf16 cvt ----
__global__ __launch_bounds__(1024) void hist_kernel(
    const float* __restrict__ ew, int* __restrict__ hmat,
    const float* __restrict__ H, ushort* __restrict__ Hb16, int do_cvt)
{
    __shared__ int h[CB];
    const int c = blockIdx.x;
    for (int i = threadIdx.x; i < CB; i += 1024) h[i] = 0;
    __syncthreads();
    int e0 = c * CHUNK;
    int e1 = e0 + CHUNK; if (e1 > NEDGE) e1 = NEDGE;
    for (int e = e0 + threadIdx.x; e < e1; e += 1024) {
        int b = e / N_EDGES;
        int src = (int)ew[(long long)e * 3];
        src = min(max(src, 0), N_NODES - 1);
        atomicAdd(&h[(b * N_NODES + src) >> 7], 1);
    }
    __syncthreads();
    for (int cb = threadIdx.x; cb < CB; cb += 1024)
        hmat[(long long)cb * NCHUNK + c] = h[cb];

    if (do_cvt) {
        const long long stride = (long long)NCHUNK * 1024 * 4;
        for (long long i = ((long long)c * 1024 + threadIdx.x) * 4; i < NHEL;
             i += stride) {
            float4 f = *(const float4*)(H + i);
            ushort4 u;
            uint v;
            v = __float_as_uint(f.x); u.x = (ushort)((v + 0x7FFF + ((v >> 16) & 1)) >> 16);
            v = __float_as_uint(f.y); u.y = (ushort)((v + 0x7FFF + ((v >> 16) & 1)) >> 16);
            v = __float_as_uint(f.z); u.z = (ushort)((v + 0x7FFF + ((v >> 16) & 1)) >> 16);
            v = __float_as_uint(f.w); u.w = (ushort)((v + 0x7FFF + ((v >> 16) & 1)) >> 16);
            *(ushort4*)(Hb16 + i) = u;
        }
    }
}

// ---------- Phase 2: exclusive scan over NTOT (scan3 fused into consumers) -
__global__ __launch_bounds__(SCAN_B) void scan1_kernel(
    int* __restrict__ data, int* __restrict__ bsum)
{
    __shared__ int sm[SCAN_B];
    int i = blockIdx.x * SCAN_B + threadIdx.x;
    int v = (i < NELEM) ? data[i] : 0;
    sm[threadIdx.x] = v;
    __syncthreads();
    for (int off = 1; off < SCAN_B; off <<= 1) {
        int t = (threadIdx.x >= off) ? sm[threadIdx.x - off] : 0;
        __syncthreads();
        sm[threadIdx.x] += t;
        __syncthreads();
    }
    if (i < NTOT) data[i] = sm[threadIdx.x] - v;
    if (threadIdx.x == SCAN_B - 1) bsum[blockIdx.x] = sm[SCAN_B - 1];
}

__global__ __launch_bounds__(512) void scan2_kernel(int* __restrict__ bsum)
{
    __shared__ int sm[512];
    int v = (threadIdx.x < NB1) ? bsum[threadIdx.x] : 0;
    sm[threadIdx.x] = v;
    __syncthreads();
    for (int off = 1; off < 512; off <<= 1) {
        int t = (threadIdx.x >= off) ? sm[threadIdx.x - off] : 0;
        __syncthreads();
        sm[threadIdx.x] += t;
        __syncthreads();
    }
    if (threadIdx.x < NB1) bsum[threadIdx.x] = sm[threadIdx.x] - v;
}

// ---------- Phase 3: partitioned scatter into coarse buckets ----------
// pair.x = (sl<<18) | gdst  where sl = seg&127, gdst = b*N_NODES+dst (<2^18)
// pair.y = bits(w). scan3 fused: global offset = offs[x] + bsum[x>>10].
__global__ __launch_bounds__(1024) void scatter_kernel(
    const float* __restrict__ ew, const int* __restrict__ offs,
    const int* __restrict__ bsum, int2* __restrict__ pair)
{
    __shared__ int lcur[CB];
    const int c = blockIdx.x;
    for (int i = threadIdx.x; i < CB; i += 1024) lcur[i] = 0;
    __syncthreads();
    int e0 = c * CHUNK;
    int e1 = e0 + CHUNK; if (e1 > NEDGE) e1 = NEDGE;
    for (int e = e0 + threadIdx.x; e < e1; e += 1024) {
        long long eb = (long long)e * 3;
        int b = e / N_EDGES;
        int src = (int)ew[eb];
        int dst = (int)ew[eb + 1];
        float w = ew[eb + 2];
        src = min(max(src, 0), N_NODES - 1);
        dst = min(max(dst, 0), N_NODES - 1);
        int seg = b * N_NODES + src;
        int cb = seg >> 7, sl = seg & (SPB - 1);
        long long oi = (long long)cb * NCHUNK + c;
        int pos = offs[oi] + bsum[(int)(oi >> 10)] + atomicAdd(&lcur[cb], 1);
        pos = min(max(pos, 0), NEDGE - 1);
        int2 v; v.x = (sl << 18) | (b * N_NODES + dst); v.y = __float_as_int(w);
        pair[pos] = v;
    }
}

// ---------- Phase 4: fused counting-sort (LDS) + register gather ----------
// One block per bucket. Sort bucket's edges into LDS by segment slot (int
// LDS atomics only), then 8 waves x 16 segments each accumulate in VGPRs:
// half-wave = edge parity, sub-lane = feature pair (uint = 2 bf16 feats).
__global__ __launch_bounds__(512) void sortgather_bf16(
    const ushort* __restrict__ Hb16, const int* __restrict__ hmat,
    const int* __restrict__ bsum, const int2* __restrict__ pair,
    float* __restrict__ out)
{
    __shared__ int2 sps[CAP];          // 16 KB sorted pairs
    __shared__ int cnt[SPB];
    __shared__ int scn[SPB];
    __shared__ int lcur[SPB];
    const int cb = blockIdx.x;
    const int tid = threadIdx.x;

    long long i0 = (long long)cb * NCHUNK;
    long long i1 = i0 + NCHUNK;                 // cb=CB-1 -> sentinel
    int base = hmat[i0] + bsum[(int)(i0 >> 10)];
    int endv = hmat[i1] + bsum[(int)(i1 >> 10)];
    base = min(max(base, 0), NEDGE);
    endv = min(max(endv, base), NEDGE);
    int nb = endv - base; if (nb > CAP) nb = CAP;

    for (int i = tid; i < SPB; i += 512) { cnt[i] = 0; lcur[i] = 0; }
    __syncthreads();
    // pass 1: histogram (also warms pair region into L1/L2)
    for (int i = tid; i < nb; i += 512) {
        int2 v = pair[base + i];
        atomicAdd(&cnt[(v.x >> 18) & (SPB - 1)], 1);
    }
    __syncthreads();
    // exclusive scan of cnt -> scn
    if (tid < SPB) scn[tid] = cnt[tid];
    __syncthreads();
    for (int off = 1; off < SPB; off <<= 1) {
        int t = (tid < SPB && tid >= off) ? scn[tid - off] : 0;
        __syncthreads();
        if (tid < SPB) scn[tid] += t;
        __syncthreads();
    }
    if (tid < SPB) scn[tid] -= cnt[tid];
    __syncthreads();
    // pass 2: scatter into sorted LDS (pair re-read is L2-hot)
    for (int i = tid; i < nb; i += 512) {
        int2 v = pair[base + i];
        int sl = (v.x >> 18) & (SPB - 1);
        int pos = scn[sl] + atomicAdd(&lcur[sl], 1);
        pos = min(max(pos, 0), CAP - 1);
        sps[pos] = v;
    }
    __syncthreads();

    // gather: wave w owns segments w*16 .. w*16+15
    const int wid  = tid >> 6;
    const int lane = tid & 63;
    const int half = lane >> 5;
    const int sub  = lane & 31;
    const uint* H32 = (const uint*)Hb16;

    for (int s = 0; s < 16; ++s) {
        int sl = wid * 16 + s;
        int st = scn[sl];
        int en = st + cnt[sl];
        float ax = 0.f, ay = 0.f;
        for (int i = st; i < en; i += 4) {
            int e0 = i + half;
            int e1 = i + 2 + half;
            int2 p0 = sps[(e0 < en) ? e0 : st];
            int2 p1 = sps[(e1 < en) ? e1 : st];
            uint a0 = ((uint)(p0.x & 0x3FFFF) << 5) + sub;
            uint a1 = ((uint)(p1.x & 0x3FFFF) << 5) + sub;
            uint h0 = H32[a0];
            uint h1 = H32[a1];
            float w0 = (e0 < en) ? __int_as_float(p0.y) : 0.0f;
            float w1 = (e1 < en) ? __int_as_float(p1.y) : 0.0f;
            ax = fmaf(w0, __uint_as_float(h0 << 16), ax);
            ay = fmaf(w0, __uint_as_float(h0 & 0xFFFF0000u), ay);
            ax = fmaf(w1, __uint_as_float(h1 << 16), ax);
            ay = fmaf(w1, __uint_as_float(h1 & 0xFFFF0000u), ay);
        }
        ax += __shfl_xor(ax, 32, 64);
        ay += __shfl_xor(ay, 32, 64);
        int seg = (cb << 7) + sl;
        if (half == 0 && seg < NSEG) {
            float2 v2; v2.x = ax; v2.y = ay;
            ((float2*)out)[((long long)seg << 5) + sub] = v2;
        }
    }

    // overflow tail (never taken for this input; keeps any input correct)
    __syncthreads();
    if (endv - base > CAP) {
        for (int e = base + CAP + wid; e < endv; e += 8) {
            int2 v = pair[e];
            int sl = (v.x >> 18) & (SPB - 1);
            int seg = (cb << 7) + sl;
            if (seg >= NSEG) continue;
            float w = __int_as_float(v.y);
            uint hv = H32[(((uint)(v.x & 0x3FFFF)) << 5) + (lane >> 1)];
            float h = (lane & 1) ? __uint_as_float(hv & 0xFFFF0000u)
                                 : __uint_as_float(hv << 16);
            atomicAdd(&out[((long long)seg << 6) + lane], w * h);
        }
    }
}

// fp32 variant (workspace too small for the bf16 mirror)
__global__ __launch_bounds__(512) void sortgather_f32(
    const float* __restrict__ H, const int* __restrict__ hmat,
    const int* __restrict__ bsum, const int2* __restrict__ pair,
    float* __restrict__ out)
{
    __shared__ int2 sps[CAP];
    __shared__ int cnt[SPB];
    __shared__ int scn[SPB];
    __shared__ int lcur[SPB];
    const int cb = blockIdx.x;
    const int tid = threadIdx.x;

    long long i0 = (long long)cb * NCHUNK;
    long long i1 = i0 + NCHUNK;
    int base = hmat[i0] + bsum[(int)(i0 >> 10)];
    int endv = hmat[i1] + bsum[(int)(i1 >> 10)];
    base = min(max(base, 0), NEDGE);
    endv = min(max(endv, base), NEDGE);
    int nb = endv - base; if (nb > CAP) nb = CAP;

    for (int i = tid; i < SPB; i += 512) { cnt[i] = 0; lcur[i] = 0; }
    __syncthreads();
    for (int i = tid; i < nb; i += 512) {
        int2 v = pair[base + i];
        atomicAdd(&cnt[(v.x >> 18) & (SPB - 1)], 1);
    }
    __syncthreads();
    if (tid < SPB) scn[tid] = cnt[tid];
    __syncthreads();
    for (int off = 1; off < SPB; off <<= 1) {
        int t = (tid < SPB && tid >= off) ? scn[tid - off] : 0;
        __syncthreads();
        if (tid < SPB) scn[tid] += t;
        __syncthreads();
    }
    if (tid < SPB) scn[tid] -= cnt[tid];
    __syncthreads();
    for (int i = tid; i < nb; i += 512) {
        int2 v = pair[base + i];
        int sl = (v.x >> 18) & (SPB - 1);
        int pos = scn[sl] + atomicAdd(&lcur[sl], 1);
        pos = min(max(pos, 0), CAP - 1);
        sps[pos] = v;
    }
    __syncthreads();

    const int wid  = tid >> 6;
    const int lane = tid & 63;
    const int half = lane >> 5;
    const int sub  = lane & 31;
    const float2* H2 = (const float2*)H;

    for (int s = 0; s < 16; ++s) {
        int sl = wid * 16 + s;
        int st = scn[sl];
        int en = st + cnt[sl];
        float ax = 0.f, ay = 0.f;
        for (int i = st; i < en; i += 4) {
            int e0 = i + half;
            int e1 = i + 2 + half;
            int2 p0 = sps[(e0 < en) ? e0 : st];
            int2 p1 = sps[(e1 < en) ? e1 : st];
            uint a0 = ((uint)(p0.x & 0x3FFFF) << 5) + sub;
            uint a1 = ((uint)(p1.x & 0x3FFFF) << 5) + sub;
            float2 h0 = H2[a0];
            float2 h1 = H2[a1];
            float w0 = (e0 < en) ? __int_as_float(p0.y) : 0.0f;
            float w1 = (e1 < en) ? __int_as_float(p1.y) : 0.0f;
            ax = fmaf(w0, h0.x, ax);
            ay = fmaf(w0, h0.y, ay);
            ax = fmaf(w1, h1.x, ax);
            ay = fmaf(w1, h1.y, ay);
        }
        ax += __shfl_xor(ax, 32, 64);
        ay += __shfl_xor(ay, 32, 64);
        int seg = (cb << 7) + sl;
        if (half == 0 && seg < NSEG) {
            float2 v2; v2.x = ax; v2.y = ay;
            ((float2*)out)[((long long)seg << 5) + sub] = v2;
        }
    }

    __syncthreads();
    if (endv - base > CAP) {
        for (int e = base + CAP + wid; e < endv; e += 8) {
            int2 v = pair[e];
            int sl = (v.x >> 18) & (SPB - 1);
            int seg = (cb << 7) + sl;
            if (seg >= NSEG) continue;
            float w = __int_as_float(v.y);
            float h = H[(((long long)(v.x & 0x3FFFF)) << 6) + lane];
            atomicAdd(&out[((long long)seg << 6) + lane], w * h);
        }
    }
}

// ---------- Fallback path (ws too small): zero + atomic scatter ----------
__global__ __launch_bounds__(256) void zero_kernel(int* __restrict__ p, long long n)
{
    long long i = (long long)blockIdx.x * blockDim.x + threadIdx.x;
    if (i < n) p[i] = 0;
}

__global__ __launch_bounds__(256) void atomic_kernel(
    const float* __restrict__ H, const float* __restrict__ ew,
    float* __restrict__ out)
{
    const long long gid = (long long)blockIdx.x * blockDim.x + threadIdx.x;
    const long long wave = gid >> 6;
    const int lane = threadIdx.x & 63;
    if (wave >= (long long)NEDGE) return;
    const int b = (int)(wave / N_EDGES);
    const long long ebase = wave * 3;
    const int src = (int)ew[ebase + 0];
    const int dst = (int)ew[ebase + 1];
    const float w = ew[ebase + 2];
    atomicAdd(&out[((long long)b * N_NODES + src) * H_SIZE + lane],
              w * H[((long long)b * N_NODES + dst) * H_SIZE + lane]);
}

extern "C" void kernel_launch(void* const* d_in, const int* in_sizes, int n_in,
                              void* d_out, int out_size, void* d_ws, size_t ws_size,
                              hipStream_t stream) {
    const float* H  = (const float*)d_in[0];   // (B, N, 64) fp32
    const float* ew = (const float*)d_in[1];   // (B, E, 3) fp32
    float* out = (float*)d_out;                // (B, N, 64) fp32

    // ws layout: hmat[NTOT] | bsum[512] | (8B-align) pair[NEDGE]int2 |
    //            (128B-align) Hb16[12.8M ushort]
    const size_t ioff = (((size_t)NTOT + 512) * 4 + 7) & ~(size_t)7;
    const size_t need_base = ioff + (size_t)NEDGE * 8;
    const size_t hoff = (need_base + 127) & ~(size_t)127;
    const size_t need_full = hoff + (size_t)NHEL * 2;   // ~43.2 MB

    if (ws_size < need_base) {
        long long n = out_size;
        zero_kernel<<<(unsigned)((n + 255) / 256), 256, 0, stream>>>((int*)out, n);
        const long long total = (long long)NEDGE * 64;
        atomic_kernel<<<(unsigned)((total + 255) / 256), 256, 0, stream>>>(H, ew, out);
        return;
    }

    int* hmat = (int*)d_ws;
    int* bsum = hmat + NTOT;
    int2* pair = (int2*)((char*)d_ws + ioff);
    ushort* Hb16 = (ushort*)((char*)d_ws + hoff);

    const bool full = (ws_size >= need_full);

    hist_kernel<<<NCHUNK, 1024, 0, stream>>>(ew, hmat, H, Hb16, full ? 1 : 0);
    scan1_kernel<<<NB1, SCAN_B, 0, stream>>>(hmat, bsum);
    scan2_kernel<<<1, 512, 0, stream>>>(bsum);
    scatter_kernel<<<NCHUNK, 1024, 0, stream>>>(ew, hmat, bsum, pair);

    if (full) {
        sortgather_bf16<<<CB, 512, 0, stream>>>(Hb16, hmat, bsum, pair, out);
    } else {
        sortgather_f32<<<CB, 512, 0, stream>>>(H, hmat, bsum, pair, out);
    }
}